// Round 3
// baseline (540.017 us; speedup 1.0000x reference)
//
#include <hip/hip_runtime.h>
#include <hip/hip_bf16.h>

#define B_ 8
#define S_ 2048
#define DM 1024
#define H_ 16
#define DH 64
#define DK 384

typedef __attribute__((ext_vector_type(8))) short bf16x8;
typedef __attribute__((ext_vector_type(4))) float f32x4;

static __device__ __forceinline__ ushort f2b(float f) {
  __hip_bfloat16 h = __float2bfloat16(f);
  return *reinterpret_cast<ushort*>(&h);
}
static __device__ __forceinline__ float b2f(ushort u) {
  __hip_bfloat16 h;
  *reinterpret_cast<ushort*>(&h) = u;
  return __bfloat162float(h);
}

// ---------------- K1: projection GEMM  Y = X @ W^T (one phase: hp heads) -------
// X: [16384,1024] f32, W: [1024,1024] f32. Out bf16 [b][h_loc][s][64].
__global__ __launch_bounds__(256) void k_proj(
    const float* __restrict__ X, const float* __restrict__ Wk,
    const float* __restrict__ Wv, const float* __restrict__ Wb,
    ushort* __restrict__ kvb, int p, int hp) {
  __shared__ ushort As[128][40];
  __shared__ ushort Bs[128][40];
  const int t = threadIdx.x, lane = t & 63, w = t >> 6;
  const int wm = w >> 1, wn = w & 1;
  const int m0 = blockIdx.x * 128;
  const int n0 = p * (hp * DH) + blockIdx.y * 128;   // global output column base
  const int wsel = blockIdx.z;
  const float* W = wsel == 0 ? Wk : (wsel == 1 ? Wv : Wb);
  const size_t sect = (size_t)(B_ * hp) * S_ * DH;
  ushort* out = kvb + (size_t)wsel * sect;

  f32x4 acc[4][4] = {};
  for (int k0 = 0; k0 < DM; k0 += 32) {
    for (int q = t; q < 1024; q += 256) {
      int row = q >> 3, seg = q & 7;
      float4 v = *(const float4*)(X + (size_t)(m0 + row) * DM + k0 + seg * 4);
      ushort4 u = { f2b(v.x), f2b(v.y), f2b(v.z), f2b(v.w) };
      *(ushort4*)&As[row][seg * 4] = u;
      float4 vw = *(const float4*)(W + (size_t)(n0 + row) * DM + k0 + seg * 4);
      ushort4 uw = { f2b(vw.x), f2b(vw.y), f2b(vw.z), f2b(vw.w) };
      *(ushort4*)&Bs[row][seg * 4] = uw;
    }
    __syncthreads();
    const int kf = (lane >> 4) * 8;
    bf16x8 af[4], bfr[4];
    #pragma unroll
    for (int mi = 0; mi < 4; mi++)
      af[mi] = *(const bf16x8*)&As[wm * 64 + mi * 16 + (lane & 15)][kf];
    #pragma unroll
    for (int ni = 0; ni < 4; ni++)
      bfr[ni] = *(const bf16x8*)&Bs[wn * 64 + ni * 16 + (lane & 15)][kf];
    #pragma unroll
    for (int mi = 0; mi < 4; mi++)
      #pragma unroll
      for (int ni = 0; ni < 4; ni++)
        acc[mi][ni] = __builtin_amdgcn_mfma_f32_16x16x32_bf16(af[mi], bfr[ni], acc[mi][ni], 0, 0, 0);
    __syncthreads();
  }
  #pragma unroll
  for (int mi = 0; mi < 4; mi++)
    #pragma unroll
    for (int ni = 0; ni < 4; ni++)
      #pragma unroll
      for (int r = 0; r < 4; r++) {
        int m = m0 + wm * 64 + mi * 16 + (lane >> 4) * 4 + r;
        int o = n0 + wn * 64 + ni * 16 + (lane & 15);
        float val = acc[mi][ni][r];
        if (wsel == 2) val = 1.0f / (1.0f + __expf(-val));
        int b = m >> 11, s = m & 2047;
        int h_loc = (o >> 6) - p * hp, d = o & 63;
        out[(((size_t)(b * hp + h_loc)) * S_ + s) * DH + d] = f2b(val);
      }
}

// ---------------- K2: DPFP + L2-normalize + denom -------------------------------
__global__ __launch_bounds__(256) void k_dpfp(
    const ushort* __restrict__ Kb, const float* __restrict__ z,
    ushort* __restrict__ mk, float* __restrict__ denom, int p, int hp) {
  __shared__ float xs[4][128];
  const int lane = threadIdx.x & 63, w = threadIdx.x >> 6;
  const size_t row = (size_t)blockIdx.x * 4 + w;     // local row: bh_loc*S + s
  float kf = b2f(Kb[row * 64 + lane]);
  xs[w][lane] = fmaxf(kf, 0.0f);
  xs[w][64 + lane] = fmaxf(-kf, 0.0f);
  __syncthreads();
  float v[6];
  float ssq = 0.0f;
  #pragma unroll
  for (int tt = 0; tt < 6; tt++) {
    int e = tt * 64 + lane;
    int j = e >> 7, i = e & 127;
    float val = xs[w][i] * xs[w][(i - j - 1) & 127];
    v[tt] = val;
    ssq += val * val;
  }
  #pragma unroll
  for (int off = 32; off > 0; off >>= 1) ssq += __shfl_xor(ssq, off);
  float inv = 1.0f / fmaxf(sqrtf(ssq), 1e-12f);
  const int bh_loc = (int)(row >> 11);
  const int bh_g = (bh_loc / hp) * H_ + p * hp + (bh_loc % hp);
  const float* zp = z + (size_t)bh_g * DK;
  float ds = 0.0f;
  #pragma unroll
  for (int tt = 0; tt < 6; tt++) {
    int e = tt * 64 + lane;
    float nv = v[tt] * inv;
    ds += zp[e] * nv;
    mk[row * DK + e] = f2b(nv);
  }
  #pragma unroll
  for (int off = 32; off > 0; off >>= 1) ds += __shfl_xor(ds, off);
  if (lane == 0) denom[row] = ds + 1e-5f;
}

// ---------------- K3: num = mk @ Wmem, gated = (V - num/den)*Bg (in-place V) ----
__global__ __launch_bounds__(256) void k_numgate(
    const ushort* __restrict__ mk, const float* __restrict__ Wmem,
    const float* __restrict__ denom, ushort* vg,
    const ushort* __restrict__ Bg, int p, int hp) {
  __shared__ ushort WmT[64][392];   // [d][k] transposed, padded
  __shared__ ushort mkS[128][40];
  const int t = threadIdx.x, lane = t & 63, w = t >> 6;
  const int bh_loc = blockIdx.y, m0 = blockIdx.x * 128;
  const int bh_g = (bh_loc / hp) * H_ + p * hp + (bh_loc % hp);
  const float* Wm = Wmem + (size_t)bh_g * DK * DH;
  for (int q = t; q < DK * DH; q += 256) {
    int kk = q >> 6, d = q & 63;
    WmT[d][kk] = f2b(Wm[q]);
  }
  __syncthreads();
  f32x4 acc[2][4] = {};
  const int kf = (lane >> 4) * 8;
  for (int k0 = 0; k0 < DK; k0 += 32) {
    for (int q = t; q < 512; q += 256) {
      int row = q >> 2, seg = q & 3;
      *(uint4*)&mkS[row][seg * 8] =
          *(const uint4*)(mk + ((size_t)bh_loc * S_ + m0 + row) * DK + k0 + seg * 8);
    }
    __syncthreads();
    bf16x8 af[2], bfr[4];
    #pragma unroll
    for (int mi = 0; mi < 2; mi++)
      af[mi] = *(const bf16x8*)&mkS[w * 32 + mi * 16 + (lane & 15)][kf];
    #pragma unroll
    for (int ni = 0; ni < 4; ni++)
      bfr[ni] = *(const bf16x8*)&WmT[ni * 16 + (lane & 15)][k0 + kf];
    #pragma unroll
    for (int mi = 0; mi < 2; mi++)
      #pragma unroll
      for (int ni = 0; ni < 4; ni++)
        acc[mi][ni] = __builtin_amdgcn_mfma_f32_16x16x32_bf16(af[mi], bfr[ni], acc[mi][ni], 0, 0, 0);
    __syncthreads();
  }
  #pragma unroll
  for (int mi = 0; mi < 2; mi++)
    #pragma unroll
    for (int ni = 0; ni < 4; ni++)
      #pragma unroll
      for (int r = 0; r < 4; r++) {
        int s = m0 + w * 32 + mi * 16 + (lane >> 4) * 4 + r;
        size_t rg = (size_t)bh_loc * S_ + s;
        int d = ni * 16 + (lane & 15);
        float num = acc[mi][ni][r];
        float den = denom[rg];
        float vv = b2f(vg[rg * 64 + d]);
        float bg = b2f(Bg[rg * 64 + d]);
        vg[rg * 64 + d] = f2b((vv - num / den) * bg);
      }
}

// ---------------- K4: assoc partial = mk^T @ gated (split-K over sk segments) ---
__global__ __launch_bounds__(256) void k_assoc(
    const ushort* __restrict__ mk, const ushort* __restrict__ gated,
    float* __restrict__ part, int sk, int s_len) {
  __shared__ ushort mkL[32][392];   // natural [s][kdim], padded
  __shared__ ushort gL[32][72];     // natural [s][d], padded
  const int t = threadIdx.x, lane = t & 63, w = t >> 6;
  const int bh_loc = blockIdx.y, seg = blockIdx.x;
  f32x4 acc[6][4] = {};
  const int kf = (lane >> 4) * 8;
  for (int s0 = seg * s_len; s0 < (seg + 1) * s_len; s0 += 32) {
    {
      int row = t >> 3, c0 = t & 7;
      const ushort* gsrc = mk + ((size_t)bh_loc * S_ + s0 + row) * DK;
      #pragma unroll
      for (int i = 0; i < 6; i++) {
        int c = c0 + 8 * i;
        *(uint4*)&mkL[row][c * 8] = *(const uint4*)(gsrc + c * 8);
      }
      *(uint4*)&gL[row][c0 * 8] =
          *(const uint4*)(gated + ((size_t)bh_loc * S_ + s0 + row) * DH + c0 * 8);
    }
    __syncthreads();
    bf16x8 af[6], bfr[4];
    #pragma unroll
    for (int mi = 0; mi < 6; mi++) {
      int m = w * 96 + mi * 16 + (lane & 15);
      bf16x8 a;
      #pragma unroll
      for (int j = 0; j < 8; j++) a[j] = (short)mkL[kf + j][m];
      af[mi] = a;
    }
    #pragma unroll
    for (int ni = 0; ni < 4; ni++) {
      int n = ni * 16 + (lane & 15);
      bf16x8 b;
      #pragma unroll
      for (int j = 0; j < 8; j++) b[j] = (short)gL[kf + j][n];
      bfr[ni] = b;
    }
    #pragma unroll
    for (int mi = 0; mi < 6; mi++)
      #pragma unroll
      for (int ni = 0; ni < 4; ni++)
        acc[mi][ni] = __builtin_amdgcn_mfma_f32_16x16x32_bf16(af[mi], bfr[ni], acc[mi][ni], 0, 0, 0);
    __syncthreads();
  }
  float* pb = part + ((size_t)bh_loc * sk + seg) * DK * DH;
  #pragma unroll
  for (int mi = 0; mi < 6; mi++)
    #pragma unroll
    for (int ni = 0; ni < 4; ni++)
      #pragma unroll
      for (int r = 0; r < 4; r++) {
        int m = w * 96 + mi * 16 + (lane >> 4) * 4 + r;
        int d = ni * 16 + (lane & 15);
        pb[(size_t)m * DH + d] = acc[mi][ni][r];
      }
}

// ---------------- K5: out = Wmem + sum(parts) ----------------------------------
__global__ __launch_bounds__(256) void k_reduce(
    const float* __restrict__ Wmem, const float* __restrict__ part,
    float* __restrict__ out, int p, int hp, int sk) {
  size_t idx = (size_t)blockIdx.x * 256 + threadIdx.x;  // over bhl*DK*DH
  int bh_loc = (int)(idx / (DK * DH));
  size_t r = idx - (size_t)bh_loc * (DK * DH);
  int bh_g = (bh_loc / hp) * H_ + p * hp + (bh_loc % hp);
  float acc = Wmem[(size_t)bh_g * (DK * DH) + r];
  for (int k = 0; k < sk; k++)
    acc += part[((size_t)bh_loc * sk + k) * (DK * DH) + r];
  out[(size_t)bh_g * (DK * DH) + r] = acc;
}

extern "C" void kernel_launch(void* const* d_in, const int* in_sizes, int n_in,
                              void* d_out, int out_size, void* d_ws, size_t ws_size,
                              hipStream_t stream) {
  const float* X  = (const float*)d_in[0];
  const float* Wk = (const float*)d_in[1];
  const float* Wv = (const float*)d_in[2];
  const float* Wb = (const float*)d_in[3];
  const float* Wm = (const float*)d_in[4];
  const float* z  = (const float*)d_in[5];
  float* out = (float*)d_out;
  char* ws = (char*)d_ws;

  // Choose heads-per-phase from available scratch (deterministic per run).
  // need(hp): kvb 3*bhl*S*64*2  +  mk bhl*S*384*2  +  denom bhl*S*4  +  part 256*24576*4
  int hp;
  if      (ws_size >= 340000000ull) hp = 16;   // ~328 MB needed
  else if (ws_size >= 106000000ull) hp = 4;    // ~101 MB needed
  else                              hp = 2;    // ~63 MB needed
  const int bhl = B_ * hp;        // local (b,h) groups per phase
  const int nph = H_ / hp;        // phases
  const int sk  = 256 / bhl;      // split-K segments (256 blocks in k_assoc)

  const size_t sect  = (size_t)bhl * S_ * DH;          // ushorts per kvb section
  ushort* kvb   = (ushort*)(ws);
  ushort* mk    = (ushort*)(ws + 3ull * sect * 2);
  float*  denom = (float*) (ws + 3ull * sect * 2 + (size_t)bhl * S_ * DK * 2);
  float*  part  = (float*) ((char*)denom + (size_t)bhl * S_ * 4);
  ushort* Kb = kvb;
  ushort* Vg = kvb + sect;        // V, overwritten with gated in K3
  ushort* Bg = kvb + 2 * sect;

  for (int p = 0; p < nph; p++) {
    k_proj   <<<dim3(128, hp / 2, 3), 256, 0, stream>>>(X, Wk, Wv, Wb, kvb, p, hp);
    k_dpfp   <<<dim3(bhl * S_ / 4), 256, 0, stream>>>(Kb, z, mk, denom, p, hp);
    k_numgate<<<dim3(16, bhl), 256, 0, stream>>>(mk, Wm, denom, Vg, Bg, p, hp);
    k_assoc  <<<dim3(sk, bhl), 256, 0, stream>>>(mk, Vg, part, sk, S_ / sk);
    k_reduce <<<dim3(bhl * DK * DH / 256), 256, 0, stream>>>(Wm, part, out, p, hp, sk);
  }
}

// Round 5
// 495.465 us; speedup vs baseline: 1.0899x; 1.0899x over previous
//
#include <hip/hip_runtime.h>
#include <hip/hip_bf16.h>

#define B_ 8
#define S_ 2048
#define DM 1024
#define H_ 16
#define DH 64
#define DK 384

#define AS3 __attribute__((address_space(3)))
#define AS1 __attribute__((address_space(1)))
typedef unsigned int u32;

typedef __attribute__((ext_vector_type(8))) short bf16x8;
typedef __attribute__((ext_vector_type(4))) float f32x4;

static __device__ __forceinline__ ushort f2b(float f) {
  __hip_bfloat16 h = __float2bfloat16(f);
  return *reinterpret_cast<ushort*>(&h);
}
static __device__ __forceinline__ float b2f(ushort u) {
  __hip_bfloat16 h;
  *reinterpret_cast<ushort*>(&h) = u;
  return __bfloat162float(h);
}

// ---------------- K0: convert X and Wk/Wv/Wb to bf16 (once) --------------------
// Virtual concat of 8-elem chunks: X = 2,097,152 chunks, each W = 131,072.
__global__ __launch_bounds__(256) void k_cvt(
    const float* __restrict__ X, const float* __restrict__ Wk,
    const float* __restrict__ Wv, const float* __restrict__ Wb,
    ushort* __restrict__ Xb, ushort* __restrict__ Wball) {
  const int total = 2097152 + 3 * 131072;
  int c = blockIdx.x * 256 + threadIdx.x;
  const int stride = gridDim.x * 256;
  for (; c < total; c += stride) {
    const float* s;
    ushort* d;
    size_t off;
    if (c < 2097152) { s = X; d = Xb; off = (size_t)c; }
    else {
      int cc = c - 2097152;
      int wsel = cc >> 17;            // /131072
      off = (size_t)(cc & 131071);
      s = wsel == 0 ? Wk : (wsel == 1 ? Wv : Wb);
      d = Wball + (size_t)wsel * (DM * DM);
    }
    float4 a = *(const float4*)(s + off * 8);
    float4 b = *(const float4*)(s + off * 8 + 4);
    ushort u[8] = { f2b(a.x), f2b(a.y), f2b(a.z), f2b(a.w),
                    f2b(b.x), f2b(b.y), f2b(b.z), f2b(b.w) };
    *(uint4*)(d + off * 8) = *(uint4*)u;
  }
}

// ---------------- K1: projection GEMM  Y = Xb @ Wb^T (m97-style) ---------------
// Xb: [16384,1024] bf16, Wball: 3x[1024,1024] bf16. Out bf16 [b][h_loc][s][64].
__global__ __launch_bounds__(256) void k_proj(
    const ushort* __restrict__ Xb, const ushort* __restrict__ Wball,
    ushort* __restrict__ kvb, int p, int hp) {
  __shared__ ushort As[128 * 32];
  __shared__ ushort Bs[128 * 32];
  const int t = threadIdx.x, lane = t & 63, w = t >> 6;
  const int wm = w >> 1, wn = w & 1;
  const int m0 = blockIdx.x * 128;
  const int n0 = p * (hp * DH) + blockIdx.y * 128;
  const int wsel = blockIdx.z;
  const ushort* Wmat = Wball + (size_t)wsel * (DM * DM);
  const size_t sect = (size_t)(B_ * hp) * S_ * DH;
  ushort* out = kvb + (size_t)wsel * sect;

  // Staging: inst i in 0..7 fills LDS bytes [i*1024,(i+1)*1024); lane covers
  // row r = i*16 + (lane>>2), quarter q = lane&3 (16B each). Wave w does i=w, w+4.
  const int r0 = w * 16 + (lane >> 2), r1 = (w + 4) * 16 + (lane >> 2);
  const int q8 = (lane & 3) * 8;   // ushort offset in row

  f32x4 acc[4][4] = {};
  for (int k0 = 0; k0 < DM; k0 += 32) {
    __builtin_amdgcn_global_load_lds(
        (const AS1 u32*)(Xb + (size_t)(m0 + r0) * DM + k0 + q8),
        (AS3 u32*)(As + w * 512), 16, 0, 0);
    __builtin_amdgcn_global_load_lds(
        (const AS1 u32*)(Xb + (size_t)(m0 + r1) * DM + k0 + q8),
        (AS3 u32*)(As + (w + 4) * 512), 16, 0, 0);
    __builtin_amdgcn_global_load_lds(
        (const AS1 u32*)(Wmat + (size_t)(n0 + r0) * DM + k0 + q8),
        (AS3 u32*)(Bs + w * 512), 16, 0, 0);
    __builtin_amdgcn_global_load_lds(
        (const AS1 u32*)(Wmat + (size_t)(n0 + r1) * DM + k0 + q8),
        (AS3 u32*)(Bs + (w + 4) * 512), 16, 0, 0);
    __syncthreads();
    const int kf = (lane >> 4) * 8;
    bf16x8 af[4], bfr[4];
    #pragma unroll
    for (int mi = 0; mi < 4; mi++)
      af[mi] = *(const bf16x8*)&As[(wm * 64 + mi * 16 + (lane & 15)) * 32 + kf];
    #pragma unroll
    for (int ni = 0; ni < 4; ni++)
      bfr[ni] = *(const bf16x8*)&Bs[(wn * 64 + ni * 16 + (lane & 15)) * 32 + kf];
    #pragma unroll
    for (int mi = 0; mi < 4; mi++)
      #pragma unroll
      for (int ni = 0; ni < 4; ni++)
        acc[mi][ni] = __builtin_amdgcn_mfma_f32_16x16x32_bf16(af[mi], bfr[ni], acc[mi][ni], 0, 0, 0);
    __syncthreads();
  }
  #pragma unroll
  for (int mi = 0; mi < 4; mi++)
    #pragma unroll
    for (int ni = 0; ni < 4; ni++)
      #pragma unroll
      for (int r = 0; r < 4; r++) {
        int m = m0 + wm * 64 + mi * 16 + (lane >> 4) * 4 + r;
        int o = n0 + wn * 64 + ni * 16 + (lane & 15);
        float val = acc[mi][ni][r];
        if (wsel == 2) val = 1.0f / (1.0f + __expf(-val));
        int b = m >> 11, s = m & 2047;
        int h_loc = (o >> 6) - p * hp, d = o & 63;
        out[(((size_t)(b * hp + h_loc)) * S_ + s) * DH + d] = f2b(val);
      }
}

// ---------------- K2: DPFP + L2-normalize + denom -------------------------------
__global__ __launch_bounds__(256) void k_dpfp(
    const ushort* __restrict__ Kb, const float* __restrict__ z,
    ushort* __restrict__ mk, float* __restrict__ denom, int p, int hp) {
  __shared__ float xs[4][128];
  const int lane = threadIdx.x & 63, w = threadIdx.x >> 6;
  const size_t row = (size_t)blockIdx.x * 4 + w;     // local row: bh_loc*S + s
  float kf = b2f(Kb[row * 64 + lane]);
  xs[w][lane] = fmaxf(kf, 0.0f);
  xs[w][64 + lane] = fmaxf(-kf, 0.0f);
  __syncthreads();
  float v[6];
  float ssq = 0.0f;
  #pragma unroll
  for (int tt = 0; tt < 6; tt++) {
    int e = tt * 64 + lane;
    int j = e >> 7, i = e & 127;
    float val = xs[w][i] * xs[w][(i - j - 1) & 127];
    v[tt] = val;
    ssq += val * val;
  }
  #pragma unroll
  for (int off = 32; off > 0; off >>= 1) ssq += __shfl_xor(ssq, off);
  float inv = 1.0f / fmaxf(sqrtf(ssq), 1e-12f);
  const int bh_loc = (int)(row >> 11);
  const int bh_g = (bh_loc / hp) * H_ + p * hp + (bh_loc % hp);
  const float* zp = z + (size_t)bh_g * DK;
  float ds = 0.0f;
  #pragma unroll
  for (int tt = 0; tt < 6; tt++) {
    int e = tt * 64 + lane;
    float nv = v[tt] * inv;
    ds += zp[e] * nv;
    mk[row * DK + e] = f2b(nv);
  }
  #pragma unroll
  for (int off = 32; off > 0; off >>= 1) ds += __shfl_xor(ds, off);
  if (lane == 0) denom[row] = ds + 1e-5f;
}

// ---------------- K3: num = mk @ Wmem, gated = (V - num/den)*Bg (in-place V) ----
__global__ __launch_bounds__(256) void k_numgate(
    const ushort* __restrict__ mk, const float* __restrict__ Wmem,
    const float* __restrict__ denom, ushort* vg,
    const ushort* __restrict__ Bg, int p, int hp) {
  __shared__ ushort WmT[64][392];   // [d][k] transposed, padded
  __shared__ ushort mkS[128][40];
  const int t = threadIdx.x, lane = t & 63, w = t >> 6;
  const int bh_loc = blockIdx.y, m0 = blockIdx.x * 128;
  const int bh_g = (bh_loc / hp) * H_ + p * hp + (bh_loc % hp);
  const float* Wm = Wmem + (size_t)bh_g * DK * DH;
  for (int q = t; q < DK * DH; q += 256) {
    int kk = q >> 6, d = q & 63;
    WmT[d][kk] = f2b(Wm[q]);
  }
  __syncthreads();
  f32x4 acc[2][4] = {};
  const int kf = (lane >> 4) * 8;
  for (int k0 = 0; k0 < DK; k0 += 32) {
    for (int q = t; q < 512; q += 256) {
      int row = q >> 2, seg = q & 3;
      *(uint4*)&mkS[row][seg * 8] =
          *(const uint4*)(mk + ((size_t)bh_loc * S_ + m0 + row) * DK + k0 + seg * 8);
    }
    __syncthreads();
    bf16x8 af[2], bfr[4];
    #pragma unroll
    for (int mi = 0; mi < 2; mi++)
      af[mi] = *(const bf16x8*)&mkS[w * 32 + mi * 16 + (lane & 15)][kf];
    #pragma unroll
    for (int ni = 0; ni < 4; ni++)
      bfr[ni] = *(const bf16x8*)&WmT[ni * 16 + (lane & 15)][k0 + kf];
    #pragma unroll
    for (int mi = 0; mi < 2; mi++)
      #pragma unroll
      for (int ni = 0; ni < 4; ni++)
        acc[mi][ni] = __builtin_amdgcn_mfma_f32_16x16x32_bf16(af[mi], bfr[ni], acc[mi][ni], 0, 0, 0);
    __syncthreads();
  }
  #pragma unroll
  for (int mi = 0; mi < 2; mi++)
    #pragma unroll
    for (int ni = 0; ni < 4; ni++)
      #pragma unroll
      for (int r = 0; r < 4; r++) {
        int s = m0 + w * 32 + mi * 16 + (lane >> 4) * 4 + r;
        size_t rg = (size_t)bh_loc * S_ + s;
        int d = ni * 16 + (lane & 15);
        float num = acc[mi][ni][r];
        float den = denom[rg];
        float vv = b2f(vg[rg * 64 + d]);
        float bg = b2f(Bg[rg * 64 + d]);
        vg[rg * 64 + d] = f2b((vv - num / den) * bg);
      }
}

// ---------------- K4: assoc partial = mk^T @ gated (split-K over sk segments) ---
__global__ __launch_bounds__(256) void k_assoc(
    const ushort* __restrict__ mk, const ushort* __restrict__ gated,
    float* __restrict__ part, int sk, int s_len) {
  __shared__ ushort mkL[32][392];   // natural [s][kdim], padded
  __shared__ ushort gL[32][72];     // natural [s][d], padded
  const int t = threadIdx.x, lane = t & 63, w = t >> 6;
  const int bh_loc = blockIdx.y, seg = blockIdx.x;
  f32x4 acc[6][4] = {};
  const int kf = (lane >> 4) * 8;
  for (int s0 = seg * s_len; s0 < (seg + 1) * s_len; s0 += 32) {
    {
      int row = t >> 3, c0 = t & 7;
      const ushort* gsrc = mk + ((size_t)bh_loc * S_ + s0 + row) * DK;
      #pragma unroll
      for (int i = 0; i < 6; i++) {
        int c = c0 + 8 * i;
        *(uint4*)&mkL[row][c * 8] = *(const uint4*)(gsrc + c * 8);
      }
      *(uint4*)&gL[row][c0 * 8] =
          *(const uint4*)(gated + ((size_t)bh_loc * S_ + s0 + row) * DH + c0 * 8);
    }
    __syncthreads();
    bf16x8 af[6], bfr[4];
    #pragma unroll
    for (int mi = 0; mi < 6; mi++) {
      int m = w * 96 + mi * 16 + (lane & 15);
      bf16x8 a;
      #pragma unroll
      for (int j = 0; j < 8; j++) a[j] = (short)mkL[kf + j][m];
      af[mi] = a;
    }
    #pragma unroll
    for (int ni = 0; ni < 4; ni++) {
      int n = ni * 16 + (lane & 15);
      bf16x8 b;
      #pragma unroll
      for (int j = 0; j < 8; j++) b[j] = (short)gL[kf + j][n];
      bfr[ni] = b;
    }
    #pragma unroll
    for (int mi = 0; mi < 6; mi++)
      #pragma unroll
      for (int ni = 0; ni < 4; ni++)
        acc[mi][ni] = __builtin_amdgcn_mfma_f32_16x16x32_bf16(af[mi], bfr[ni], acc[mi][ni], 0, 0, 0);
    __syncthreads();
  }
  float* pb = part + ((size_t)bh_loc * sk + seg) * DK * DH;
  #pragma unroll
  for (int mi = 0; mi < 6; mi++)
    #pragma unroll
    for (int ni = 0; ni < 4; ni++)
      #pragma unroll
      for (int r = 0; r < 4; r++) {
        int m = w * 96 + mi * 16 + (lane >> 4) * 4 + r;
        int d = ni * 16 + (lane & 15);
        pb[(size_t)m * DH + d] = acc[mi][ni][r];
      }
}

// ---------------- K5: out = Wmem + sum(parts) ----------------------------------
__global__ __launch_bounds__(256) void k_reduce(
    const float* __restrict__ Wmem, const float* __restrict__ part,
    float* __restrict__ out, int p, int hp, int sk) {
  size_t idx = (size_t)blockIdx.x * 256 + threadIdx.x;  // over bhl*DK*DH
  int bh_loc = (int)(idx / (DK * DH));
  size_t r = idx - (size_t)bh_loc * (DK * DH);
  int bh_g = (bh_loc / hp) * H_ + p * hp + (bh_loc % hp);
  float acc = Wmem[(size_t)bh_g * (DK * DH) + r];
  for (int k = 0; k < sk; k++)
    acc += part[((size_t)bh_loc * sk + k) * (DK * DH) + r];
  out[(size_t)bh_g * (DK * DH) + r] = acc;
}

extern "C" void kernel_launch(void* const* d_in, const int* in_sizes, int n_in,
                              void* d_out, int out_size, void* d_ws, size_t ws_size,
                              hipStream_t stream) {
  const float* X  = (const float*)d_in[0];
  const float* Wk = (const float*)d_in[1];
  const float* Wv = (const float*)d_in[2];
  const float* Wb = (const float*)d_in[3];
  const float* Wm = (const float*)d_in[4];
  const float* z  = (const float*)d_in[5];
  float* out = (float*)d_out;
  char* ws = (char*)d_ws;

  // Heads-per-phase from available scratch (deterministic; ws_size >= 106 MB
  // proven by round 3's hp=4 run, so the hp=2 floor of ~103 MB always fits).
  int hp;
  if      (ws_size >= 375000000ull) hp = 16;   // needs ~368 MB, single phase
  else if (ws_size >= 145000000ull) hp = 4;    // needs ~141 MB
  else                              hp = 2;    // needs ~103 MB
  const int bhl = B_ * hp;        // local (b,h) groups per phase
  const int nph = H_ / hp;        // phases
  const int sk  = 256 / bhl;      // split-K segments (256 blocks in k_assoc)

  // ws layout: Xb | Wball | kvb(3 sect) | mk | denom | part
  const size_t sect = (size_t)bhl * S_ * DH;           // ushorts per kvb section
  ushort* Xb    = (ushort*)(ws);
  ushort* Wball = (ushort*)(ws + 33554432ull);
  char*   dyn   = ws + 33554432ull + 6291456ull;
  ushort* kvb   = (ushort*)(dyn);
  ushort* mk    = (ushort*)(dyn + 3ull * sect * 2);
  float*  denom = (float*) (dyn + 3ull * sect * 2 + (size_t)bhl * S_ * DK * 2);
  float*  part  = (float*) ((char*)denom + (size_t)bhl * S_ * 4);
  ushort* Kb = kvb;
  ushort* Vg = kvb + sect;        // V, overwritten with gated in K3
  ushort* Bg = kvb + 2 * sect;

  k_cvt<<<dim3(2048), 256, 0, stream>>>(X, Wk, Wv, Wb, Xb, Wball);
  for (int p = 0; p < nph; p++) {
    k_proj   <<<dim3(128, hp / 2, 3), 256, 0, stream>>>(Xb, Wball, kvb, p, hp);
    k_dpfp   <<<dim3(bhl * S_ / 4), 256, 0, stream>>>(Kb, z, mk, denom, p, hp);
    k_numgate<<<dim3(16, bhl), 256, 0, stream>>>(mk, Wm, denom, Vg, Bg, p, hp);
    k_assoc  <<<dim3(sk, bhl), 256, 0, stream>>>(mk, Vg, part, sk, S_ / sk);
    k_reduce <<<dim3(bhl * DK * DH / 256), 256, 0, stream>>>(Wm, part, out, p, hp, sk);
  }
}

// Round 6
// 469.765 us; speedup vs baseline: 1.1495x; 1.0547x over previous
//
#include <hip/hip_runtime.h>
#include <hip/hip_bf16.h>

#define B_ 8
#define S_ 2048
#define DM 1024
#define H_ 16
#define DH 64
#define DK 384

#define AS3 __attribute__((address_space(3)))
#define AS1 __attribute__((address_space(1)))
typedef unsigned int u32;

typedef __attribute__((ext_vector_type(8))) short bf16x8;
typedef __attribute__((ext_vector_type(4))) float f32x4;

static __device__ __forceinline__ ushort f2b(float f) {
  __hip_bfloat16 h = __float2bfloat16(f);
  return *reinterpret_cast<ushort*>(&h);
}
static __device__ __forceinline__ float b2f(ushort u) {
  __hip_bfloat16 h;
  *reinterpret_cast<ushort*>(&h) = u;
  return __bfloat162float(h);
}

// ---------------- K0: convert X and Wk/Wv/Wb to bf16 (once) --------------------
__global__ __launch_bounds__(256) void k_cvt(
    const float* __restrict__ X, const float* __restrict__ Wk,
    const float* __restrict__ Wv, const float* __restrict__ Wb,
    ushort* __restrict__ Xb, ushort* __restrict__ Wball) {
  const int total = 2097152 + 3 * 131072;
  int c = blockIdx.x * 256 + threadIdx.x;
  const int stride = gridDim.x * 256;
  for (; c < total; c += stride) {
    const float* s;
    ushort* d;
    size_t off;
    if (c < 2097152) { s = X; d = Xb; off = (size_t)c; }
    else {
      int cc = c - 2097152;
      int wsel = cc >> 17;            // /131072
      off = (size_t)(cc & 131071);
      s = wsel == 0 ? Wk : (wsel == 1 ? Wv : Wb);
      d = Wball + (size_t)wsel * (DM * DM);
    }
    float4 a = *(const float4*)(s + off * 8);
    float4 b = *(const float4*)(s + off * 8 + 4);
    ushort u[8] = { f2b(a.x), f2b(a.y), f2b(a.z), f2b(a.w),
                    f2b(b.x), f2b(b.y), f2b(b.z), f2b(b.w) };
    *(uint4*)(d + off * 8) = *(uint4*)u;
  }
}

// ---------------- K1: projection GEMM  Y = Xb @ Wb^T ---------------------------
// BK=64, XOR-swizzled LDS (pre-swizzled global source, linear global_load_lds
// dest), coalesced LDS-bounce epilogue. Out bf16 [b][h_loc][s][64].
__global__ __launch_bounds__(256) void k_proj(
    const ushort* __restrict__ Xb, const ushort* __restrict__ Wball,
    ushort* __restrict__ kvb, int p, int hp) {
  __shared__ ushort SH[2 * 128 * 64];          // As | Bs (32 KB), Cb aliases As
  ushort* As = SH;
  ushort* Bs = SH + 128 * 64;
  const int t = threadIdx.x, lane = t & 63, w = t >> 6;
  const int wm = w >> 1, wn = w & 1;
  const int m0 = blockIdx.x * 128;
  const int n0 = p * (hp * DH) + blockIdx.y * 128;
  const int wsel = blockIdx.z;
  const ushort* Wmat = Wball + (size_t)wsel * (DM * DM);
  const size_t sect = (size_t)(B_ * hp) * S_ * DH;
  ushort* out = kvb + (size_t)wsel * sect;

  // Staging: inst j of wave w fills LDS ushorts [(w*4+j)*512, +512) linearly
  // (8 rows of 64). Global source column is XOR-swizzled by row&7 so that the
  // swizzled ds_read below recovers linear k. row&7 == lane>>3 here.
  const int rowst = (lane >> 3);                      // row within 8-row chunk
  const int colsw = ((lane & 7) ^ rowst) << 3;        // swizzled 16B slot
  // Fragment read: ra&7 == lane&7; slot (lane>>4)+4*kk2 swizzled by lane&7.
  f32x4 acc[4][4] = {};
  for (int k0 = 0; k0 < DM; k0 += 64) {
    #pragma unroll
    for (int j = 0; j < 4; j++) {
      int row = (w * 4 + j) * 8 + rowst;
      __builtin_amdgcn_global_load_lds(
          (const AS1 u32*)(Xb + (size_t)(m0 + row) * DM + k0 + colsw),
          (AS3 u32*)(As + (w * 4 + j) * 512), 16, 0, 0);
      __builtin_amdgcn_global_load_lds(
          (const AS1 u32*)(Wmat + (size_t)(n0 + row) * DM + k0 + colsw),
          (AS3 u32*)(Bs + (w * 4 + j) * 512), 16, 0, 0);
    }
    __syncthreads();
    #pragma unroll
    for (int kk2 = 0; kk2 < 2; kk2++) {
      const int csw = (((lane >> 4) + 4 * kk2) ^ (lane & 7)) << 3;
      bf16x8 af[4], bfr[4];
      #pragma unroll
      for (int mi = 0; mi < 4; mi++)
        af[mi] = *(const bf16x8*)&As[(wm * 64 + mi * 16 + (lane & 15)) * 64 + csw];
      #pragma unroll
      for (int ni = 0; ni < 4; ni++)
        bfr[ni] = *(const bf16x8*)&Bs[(wn * 64 + ni * 16 + (lane & 15)) * 64 + csw];
      #pragma unroll
      for (int mi = 0; mi < 4; mi++)
        #pragma unroll
        for (int ni = 0; ni < 4; ni++)
          acc[mi][ni] = __builtin_amdgcn_mfma_f32_16x16x32_bf16(af[mi], bfr[ni], acc[mi][ni], 0, 0, 0);
    }
    __syncthreads();
  }

  // Epilogue: per mi-chunk (32 rows x 128 cols), bounce through LDS, store
  // 2x dwordx4 per thread (coalesced 32B within a head's row segment).
  ushort (*Cb)[136] = (ushort (*)[136])SH;
  #pragma unroll
  for (int mi = 0; mi < 4; mi++) {
    __syncthreads();
    #pragma unroll
    for (int ni = 0; ni < 4; ni++)
      #pragma unroll
      for (int r = 0; r < 4; r++) {
        float val = acc[mi][ni][r];
        if (wsel == 2) val = 1.0f / (1.0f + __expf(-val));
        Cb[wm * 16 + (lane >> 4) * 4 + r][wn * 64 + ni * 16 + (lane & 15)] = f2b(val);
      }
    __syncthreads();
    int rowL = t >> 3;
    int m = m0 + (rowL >> 4) * 64 + mi * 16 + (rowL & 15);
    int o0 = n0 + (t & 7) * 16;
    int b = m >> 11, s = m & 2047;
    int h_loc = (o0 >> 6) - p * hp, d = o0 & 63;
    ushort* dst = out + (((size_t)(b * hp + h_loc)) * S_ + s) * DH + d;
    uint4 v0 = *(uint4*)&Cb[rowL][(t & 7) * 16];
    uint4 v1 = *(uint4*)&Cb[rowL][(t & 7) * 16 + 8];
    *(uint4*)dst = v0;
    *(uint4*)(dst + 8) = v1;
  }
}

// ---------------- K2: DPFP + L2-normalize + denom -------------------------------
__global__ __launch_bounds__(256) void k_dpfp(
    const ushort* __restrict__ Kb, const float* __restrict__ z,
    ushort* __restrict__ mk, float* __restrict__ denom, int p, int hp) {
  __shared__ float xs[4][128];
  const int lane = threadIdx.x & 63, w = threadIdx.x >> 6;
  const size_t row = (size_t)blockIdx.x * 4 + w;     // local row: bh_loc*S + s
  float kf = b2f(Kb[row * 64 + lane]);
  xs[w][lane] = fmaxf(kf, 0.0f);
  xs[w][64 + lane] = fmaxf(-kf, 0.0f);
  __syncthreads();
  float v[6];
  float ssq = 0.0f;
  #pragma unroll
  for (int tt = 0; tt < 6; tt++) {
    int e = tt * 64 + lane;
    int j = e >> 7, i = e & 127;
    float val = xs[w][i] * xs[w][(i - j - 1) & 127];
    v[tt] = val;
    ssq += val * val;
  }
  #pragma unroll
  for (int off = 32; off > 0; off >>= 1) ssq += __shfl_xor(ssq, off);
  float inv = 1.0f / fmaxf(sqrtf(ssq), 1e-12f);
  const int bh_loc = (int)(row >> 11);
  const int bh_g = (bh_loc / hp) * H_ + p * hp + (bh_loc % hp);
  const float* zp = z + (size_t)bh_g * DK;
  float ds = 0.0f;
  #pragma unroll
  for (int tt = 0; tt < 6; tt++) {
    int e = tt * 64 + lane;
    float nv = v[tt] * inv;
    ds += zp[e] * nv;
    mk[row * DK + e] = f2b(nv);
  }
  #pragma unroll
  for (int off = 32; off > 0; off >>= 1) ds += __shfl_xor(ds, off);
  if (lane == 0) denom[row] = ds + 1e-5f;
}

// ---------------- K3: num = mk @ Wmem, gated = (V - num/den)*Bg (in-place V) ----
__global__ __launch_bounds__(256) void k_numgate(
    const ushort* __restrict__ mk, const float* __restrict__ Wmem,
    const float* __restrict__ denom, ushort* vg,
    const ushort* __restrict__ Bg, int p, int hp) {
  __shared__ ushort WmT[64][392];   // [d][k] transposed, padded
  __shared__ ushort mkS[128][40];
  const int t = threadIdx.x, lane = t & 63, w = t >> 6;
  const int bh_loc = blockIdx.y, m0 = blockIdx.x * 128;
  const int bh_g = (bh_loc / hp) * H_ + p * hp + (bh_loc % hp);
  const float* Wm = Wmem + (size_t)bh_g * DK * DH;
  for (int q = t; q < DK * DH; q += 256) {
    int kk = q >> 6, d = q & 63;
    WmT[d][kk] = f2b(Wm[q]);
  }
  __syncthreads();
  f32x4 acc[2][4] = {};
  const int kf = (lane >> 4) * 8;
  for (int k0 = 0; k0 < DK; k0 += 32) {
    for (int q = t; q < 512; q += 256) {
      int row = q >> 2, seg = q & 3;
      *(uint4*)&mkS[row][seg * 8] =
          *(const uint4*)(mk + ((size_t)bh_loc * S_ + m0 + row) * DK + k0 + seg * 8);
    }
    __syncthreads();
    bf16x8 af[2], bfr[4];
    #pragma unroll
    for (int mi = 0; mi < 2; mi++)
      af[mi] = *(const bf16x8*)&mkS[w * 32 + mi * 16 + (lane & 15)][kf];
    #pragma unroll
    for (int ni = 0; ni < 4; ni++)
      bfr[ni] = *(const bf16x8*)&WmT[ni * 16 + (lane & 15)][k0 + kf];
    #pragma unroll
    for (int mi = 0; mi < 2; mi++)
      #pragma unroll
      for (int ni = 0; ni < 4; ni++)
        acc[mi][ni] = __builtin_amdgcn_mfma_f32_16x16x32_bf16(af[mi], bfr[ni], acc[mi][ni], 0, 0, 0);
    __syncthreads();
  }
  #pragma unroll
  for (int mi = 0; mi < 2; mi++)
    #pragma unroll
    for (int ni = 0; ni < 4; ni++)
      #pragma unroll
      for (int r = 0; r < 4; r++) {
        int s = m0 + w * 32 + mi * 16 + (lane >> 4) * 4 + r;
        size_t rg = (size_t)bh_loc * S_ + s;
        int d = ni * 16 + (lane & 15);
        float num = acc[mi][ni][r];
        float den = denom[rg];
        float vv = b2f(vg[rg * 64 + d]);
        float bg = b2f(Bg[rg * 64 + d]);
        vg[rg * 64 + d] = f2b((vv - num / den) * bg);
      }
}

// ---------------- K4: assoc partial = mk^T @ gated (split-K over sk segments) ---
__global__ __launch_bounds__(256) void k_assoc(
    const ushort* __restrict__ mk, const ushort* __restrict__ gated,
    float* __restrict__ part, int sk, int s_len) {
  __shared__ ushort mkL[32][392];   // natural [s][kdim], padded
  __shared__ ushort gL[32][72];     // natural [s][d], padded
  const int t = threadIdx.x, lane = t & 63, w = t >> 6;
  const int bh_loc = blockIdx.y, seg = blockIdx.x;
  f32x4 acc[6][4] = {};
  const int kf = (lane >> 4) * 8;
  for (int s0 = seg * s_len; s0 < (seg + 1) * s_len; s0 += 32) {
    {
      int row = t >> 3, c0 = t & 7;
      const ushort* gsrc = mk + ((size_t)bh_loc * S_ + s0 + row) * DK;
      #pragma unroll
      for (int i = 0; i < 6; i++) {
        int c = c0 + 8 * i;
        *(uint4*)&mkL[row][c * 8] = *(const uint4*)(gsrc + c * 8);
      }
      *(uint4*)&gL[row][c0 * 8] =
          *(const uint4*)(gated + ((size_t)bh_loc * S_ + s0 + row) * DH + c0 * 8);
    }
    __syncthreads();
    bf16x8 af[6], bfr[4];
    #pragma unroll
    for (int mi = 0; mi < 6; mi++) {
      int m = w * 96 + mi * 16 + (lane & 15);
      bf16x8 a;
      #pragma unroll
      for (int j = 0; j < 8; j++) a[j] = (short)mkL[kf + j][m];
      af[mi] = a;
    }
    #pragma unroll
    for (int ni = 0; ni < 4; ni++) {
      int n = ni * 16 + (lane & 15);
      bf16x8 b;
      #pragma unroll
      for (int j = 0; j < 8; j++) b[j] = (short)gL[kf + j][n];
      bfr[ni] = b;
    }
    #pragma unroll
    for (int mi = 0; mi < 6; mi++)
      #pragma unroll
      for (int ni = 0; ni < 4; ni++)
        acc[mi][ni] = __builtin_amdgcn_mfma_f32_16x16x32_bf16(af[mi], bfr[ni], acc[mi][ni], 0, 0, 0);
    __syncthreads();
  }
  float* pb = part + ((size_t)bh_loc * sk + seg) * DK * DH;
  #pragma unroll
  for (int mi = 0; mi < 6; mi++)
    #pragma unroll
    for (int ni = 0; ni < 4; ni++)
      #pragma unroll
      for (int r = 0; r < 4; r++) {
        int m = w * 96 + mi * 16 + (lane >> 4) * 4 + r;
        int d = ni * 16 + (lane & 15);
        pb[(size_t)m * DH + d] = acc[mi][ni][r];
      }
}

// ---------------- K5: out = Wmem + sum(parts) ----------------------------------
__global__ __launch_bounds__(256) void k_reduce(
    const float* __restrict__ Wmem, const float* __restrict__ part,
    float* __restrict__ out, int p, int hp, int sk) {
  size_t idx = (size_t)blockIdx.x * 256 + threadIdx.x;  // over bhl*DK*DH
  int bh_loc = (int)(idx / (DK * DH));
  size_t r = idx - (size_t)bh_loc * (DK * DH);
  int bh_g = (bh_loc / hp) * H_ + p * hp + (bh_loc % hp);
  float acc = Wmem[(size_t)bh_g * (DK * DH) + r];
  for (int k = 0; k < sk; k++)
    acc += part[((size_t)bh_loc * sk + k) * (DK * DH) + r];
  out[(size_t)bh_g * (DK * DH) + r] = acc;
}

extern "C" void kernel_launch(void* const* d_in, const int* in_sizes, int n_in,
                              void* d_out, int out_size, void* d_ws, size_t ws_size,
                              hipStream_t stream) {
  const float* X  = (const float*)d_in[0];
  const float* Wk = (const float*)d_in[1];
  const float* Wv = (const float*)d_in[2];
  const float* Wb = (const float*)d_in[3];
  const float* Wm = (const float*)d_in[4];
  const float* z  = (const float*)d_in[5];
  float* out = (float*)d_out;
  char* ws = (char*)d_ws;

  // Heads-per-phase from available scratch (ws_size >= 145 MB proven by round
  // 5's hp=4 run; hp=2 floor ~103 MB always fits).
  int hp;
  if      (ws_size >= 375000000ull) hp = 16;   // needs ~368 MB, single phase
  else if (ws_size >= 145000000ull) hp = 4;    // needs ~141 MB
  else                              hp = 2;    // needs ~103 MB
  const int bhl = B_ * hp;        // local (b,h) groups per phase
  const int nph = H_ / hp;        // phases
  const int sk  = 256 / bhl;      // split-K segments (256 blocks in k_assoc)

  // ws layout: Xb | Wball | kvb(3 sect) | mk | denom | part
  const size_t sect = (size_t)bhl * S_ * DH;           // ushorts per kvb section
  ushort* Xb    = (ushort*)(ws);
  ushort* Wball = (ushort*)(ws + 33554432ull);
  char*   dyn   = ws + 33554432ull + 6291456ull;
  ushort* kvb   = (ushort*)(dyn);
  ushort* mk    = (ushort*)(dyn + 3ull * sect * 2);
  float*  denom = (float*) (dyn + 3ull * sect * 2 + (size_t)bhl * S_ * DK * 2);
  float*  part  = (float*) ((char*)denom + (size_t)bhl * S_ * 4);
  ushort* Kb = kvb;
  ushort* Vg = kvb + sect;        // V, overwritten with gated in K3
  ushort* Bg = kvb + 2 * sect;

  k_cvt<<<dim3(2048), 256, 0, stream>>>(X, Wk, Wv, Wb, Xb, Wball);
  for (int p = 0; p < nph; p++) {
    k_proj   <<<dim3(128, hp / 2, 3), 256, 0, stream>>>(Xb, Wball, kvb, p, hp);
    k_dpfp   <<<dim3(bhl * S_ / 4), 256, 0, stream>>>(Kb, z, mk, denom, p, hp);
    k_numgate<<<dim3(16, bhl), 256, 0, stream>>>(mk, Wm, denom, Vg, Bg, p, hp);
    k_assoc  <<<dim3(sk, bhl), 256, 0, stream>>>(mk, Vg, part, sk, S_ / sk);
    k_reduce <<<dim3(bhl * DK * DH / 256), 256, 0, stream>>>(Wm, part, out, p, hp, sk);
  }
}

// Round 7
// 441.352 us; speedup vs baseline: 1.2236x; 1.0644x over previous
//
#include <hip/hip_runtime.h>
#include <hip/hip_bf16.h>

#define B_ 8
#define S_ 2048
#define DM 1024
#define H_ 16
#define DH 64
#define DK 384

#define AS3 __attribute__((address_space(3)))
#define AS1 __attribute__((address_space(1)))
typedef unsigned int u32;

typedef __attribute__((ext_vector_type(8))) short bf16x8;
typedef __attribute__((ext_vector_type(4))) float f32x4;

static __device__ __forceinline__ ushort f2b(float f) {
  __hip_bfloat16 h = __float2bfloat16(f);
  return *reinterpret_cast<ushort*>(&h);
}
static __device__ __forceinline__ float b2f(ushort u) {
  __hip_bfloat16 h;
  *reinterpret_cast<ushort*>(&h) = u;
  return __bfloat162float(h);
}

// ---------------- K0: convert X and Wk/Wv/Wb to bf16 (once) --------------------
__global__ __launch_bounds__(256) void k_cvt(
    const float* __restrict__ X, const float* __restrict__ Wk,
    const float* __restrict__ Wv, const float* __restrict__ Wb,
    ushort* __restrict__ Xb, ushort* __restrict__ Wball) {
  const int total = 2097152 + 3 * 131072;
  int c = blockIdx.x * 256 + threadIdx.x;
  const int stride = gridDim.x * 256;
  for (; c < total; c += stride) {
    const float* s;
    ushort* d;
    size_t off;
    if (c < 2097152) { s = X; d = Xb; off = (size_t)c; }
    else {
      int cc = c - 2097152;
      int wsel = cc >> 17;
      off = (size_t)(cc & 131071);
      s = wsel == 0 ? Wk : (wsel == 1 ? Wv : Wb);
      d = Wball + (size_t)wsel * (DM * DM);
    }
    float4 a = *(const float4*)(s + off * 8);
    float4 b = *(const float4*)(s + off * 8 + 4);
    ushort u[8] = { f2b(a.x), f2b(a.y), f2b(a.z), f2b(a.w),
                    f2b(b.x), f2b(b.y), f2b(b.z), f2b(b.w) };
    *(uint4*)(d + off * 8) = *(uint4*)u;
  }
}

// ---------------- K1: projection GEMM  Y = Xb @ Wb^T, double-buffered ----------
// Out bf16 [b][h_store][s][64]; h_store = h_abs - hoff; row stride hstore.
__global__ __launch_bounds__(256) void k_proj(
    const ushort* __restrict__ Xb, const ushort* __restrict__ Wball,
    ushort* __restrict__ kvb, int n0_base, int hoff, int hstore) {
  __shared__ ushort SH[4 * 8192];              // As[2] | Bs[2]  (64 KB)
  ushort* As = SH;
  ushort* Bs = SH + 2 * 8192;
  const int t = threadIdx.x, lane = t & 63, w = t >> 6;
  const int wm = w >> 1, wn = w & 1;
  const int m0 = blockIdx.x * 128;
  const int n0 = n0_base + blockIdx.y * 128;
  const int wsel = blockIdx.z;
  const ushort* Wmat = Wball + (size_t)wsel * (DM * DM);
  const size_t sect = (size_t)(B_ * hstore) * S_ * DH;
  ushort* out = kvb + (size_t)wsel * sect;

  const int rowst = (lane >> 3);
  const int colsw = ((lane & 7) ^ rowst) << 3;       // pre-swizzled global col

  auto STAGE = [&](int buf, int k0) {
    #pragma unroll
    for (int j = 0; j < 4; j++) {
      int row = (w * 4 + j) * 8 + rowst;
      __builtin_amdgcn_global_load_lds(
          (const AS1 u32*)(Xb + (size_t)(m0 + row) * DM + k0 + colsw),
          (AS3 u32*)(As + buf * 8192 + (w * 4 + j) * 512), 16, 0, 0);
      __builtin_amdgcn_global_load_lds(
          (const AS1 u32*)(Wmat + (size_t)(n0 + row) * DM + k0 + colsw),
          (AS3 u32*)(Bs + buf * 8192 + (w * 4 + j) * 512), 16, 0, 0);
    }
  };

  f32x4 acc[4][4] = {};
  STAGE(0, 0);
  __syncthreads();
  int cur = 0;
  for (int kt = 0; kt < 16; kt++) {
    if (kt < 15) STAGE(cur ^ 1, (kt + 1) * 64);
    const ushort* Ab = As + cur * 8192;
    const ushort* Bb = Bs + cur * 8192;
    #pragma unroll
    for (int kk2 = 0; kk2 < 2; kk2++) {
      const int csw = (((lane >> 4) + 4 * kk2) ^ (lane & 7)) << 3;
      bf16x8 af[4], bfr[4];
      #pragma unroll
      for (int mi = 0; mi < 4; mi++)
        af[mi] = *(const bf16x8*)&Ab[(wm * 64 + mi * 16 + (lane & 15)) * 64 + csw];
      #pragma unroll
      for (int ni = 0; ni < 4; ni++)
        bfr[ni] = *(const bf16x8*)&Bb[(wn * 64 + ni * 16 + (lane & 15)) * 64 + csw];
      #pragma unroll
      for (int mi = 0; mi < 4; mi++)
        #pragma unroll
        for (int ni = 0; ni < 4; ni++)
          acc[mi][ni] = __builtin_amdgcn_mfma_f32_16x16x32_bf16(af[mi], bfr[ni], acc[mi][ni], 0, 0, 0);
    }
    __syncthreads();
    cur ^= 1;
  }

  // Epilogue: LDS bounce, coalesced 2x dwordx4 stores. Cb aliases SH.
  ushort (*Cb)[136] = (ushort (*)[136])SH;
  #pragma unroll
  for (int mi = 0; mi < 4; mi++) {
    __syncthreads();
    #pragma unroll
    for (int ni = 0; ni < 4; ni++)
      #pragma unroll
      for (int r = 0; r < 4; r++) {
        float val = acc[mi][ni][r];
        if (wsel == 2) val = 1.0f / (1.0f + __expf(-val));
        Cb[wm * 16 + (lane >> 4) * 4 + r][wn * 64 + ni * 16 + (lane & 15)] = f2b(val);
      }
    __syncthreads();
    int rowL = t >> 3;
    int m = m0 + (rowL >> 4) * 64 + mi * 16 + (rowL & 15);
    int o0 = n0 + (t & 7) * 16;
    int b = m >> 11, s = m & 2047;
    int h_st = (o0 >> 6) - hoff, d = o0 & 63;
    ushort* dst = out + (((size_t)(b * hstore + h_st)) * S_ + s) * DH + d;
    uint4 v0 = *(uint4*)&Cb[rowL][(t & 7) * 16];
    uint4 v1 = *(uint4*)&Cb[rowL][(t & 7) * 16 + 8];
    *(uint4*)dst = v0;
    *(uint4*)(dst + 8) = v1;
  }
}

// ---------------- K2: DPFP + L2-normalize + denom -------------------------------
__global__ __launch_bounds__(256) void k_dpfp(
    const ushort* __restrict__ Kb, const float* __restrict__ z,
    ushort* __restrict__ mk, float* __restrict__ denom,
    int p, int hpd, int hstore, int sglob) {
  __shared__ float xs[4][128];
  const int lane = threadIdx.x & 63, w = threadIdx.x >> 6;
  const size_t row = (size_t)blockIdx.x * 4 + w;     // phase-local bh_loc*S + s
  const int bh_loc = (int)(row >> 11), s = (int)(row & 2047);
  const int b = bh_loc / hpd, h_l = bh_loc % hpd;
  const int h_g = p * hpd + h_l;
  const int sh = sglob ? h_g : h_l;
  const size_t krow = ((size_t)(b * hstore + sh)) * S_ + s;
  float kf = b2f(Kb[krow * 64 + lane]);
  xs[w][lane] = fmaxf(kf, 0.0f);
  xs[w][64 + lane] = fmaxf(-kf, 0.0f);
  __syncthreads();
  float v[6];
  float ssq = 0.0f;
  #pragma unroll
  for (int tt = 0; tt < 6; tt++) {
    int e = tt * 64 + lane;
    int j = e >> 7, i = e & 127;
    float val = xs[w][i] * xs[w][(i - j - 1) & 127];
    v[tt] = val;
    ssq += val * val;
  }
  #pragma unroll
  for (int off = 32; off > 0; off >>= 1) ssq += __shfl_xor(ssq, off);
  float inv = 1.0f / fmaxf(sqrtf(ssq), 1e-12f);
  const int bh_g = b * H_ + h_g;
  const float* zp = z + (size_t)bh_g * DK;
  float ds = 0.0f;
  #pragma unroll
  for (int tt = 0; tt < 6; tt++) {
    int e = tt * 64 + lane;
    float nv = v[tt] * inv;
    ds += zp[e] * nv;
    mk[row * DK + e] = f2b(nv);
  }
  #pragma unroll
  for (int off = 32; off > 0; off >>= 1) ds += __shfl_xor(ds, off);
  if (lane == 0) denom[row] = ds + 1e-5f;
}

// ---------------- K3: fused num+gate+assoc -------------------------------------
// Per (seg, bh_loc): stage WmT; per 32-row chunk: num = mk@Wm^T (one frag/wave),
// gate in-register -> gL, assoc += mk^T @ gL (48 DK-rows/wave).
__global__ __launch_bounds__(512) void k_fused(
    const ushort* __restrict__ mk, const float* __restrict__ Wmem,
    const float* __restrict__ denom, const ushort* __restrict__ Vb,
    const ushort* __restrict__ Bgb, float* __restrict__ part,
    int p, int hpd, int hstore, int sglob, int sk, int s_len) {
  __shared__ ushort WmT[64][392];
  __shared__ ushort mkL[32][392];
  __shared__ ushort gL[32][72];
  const int t = threadIdx.x, lane = t & 63, w = t >> 6;
  const int bh_loc = blockIdx.y, seg = blockIdx.x;
  const int b = bh_loc / hpd, h_l = bh_loc % hpd;
  const int h_g = p * hpd + h_l;
  const int bh_g = b * H_ + h_g;
  const int sh = sglob ? h_g : h_l;
  const size_t vbase = ((size_t)(b * hstore + sh)) * S_;
  const float* Wm = Wmem + (size_t)bh_g * (DK * DH);
  for (int q = t; q < DK * DH; q += 512) {
    int kk = q >> 6, d = q & 63;
    WmT[d][kk] = f2b(Wm[q]);
  }
  const int kf = (lane >> 4) * 8;
  const int mi = w >> 2, ni = w & 3;       // num-phase fragment of this wave
  f32x4 acc[3][4] = {};
  __syncthreads();
  for (int s0 = seg * s_len; s0 < (seg + 1) * s_len; s0 += 32) {
    #pragma unroll
    for (int i = 0; i < 3; i++) {
      int idx = t + 512 * i;
      int row = idx / 48, c = idx - row * 48;
      *(uint4*)&mkL[row][c * 8] =
          *(const uint4*)(mk + ((size_t)bh_loc * S_ + s0 + row) * DK + c * 8);
    }
    __syncthreads();
    // num: one 16x16 frag per wave over K=384
    f32x4 an = {};
    #pragma unroll
    for (int k0 = 0; k0 < DK; k0 += 32) {
      bf16x8 af = *(const bf16x8*)&mkL[mi * 16 + (lane & 15)][k0 + kf];
      bf16x8 bw = *(const bf16x8*)&WmT[ni * 16 + (lane & 15)][k0 + kf];
      an = __builtin_amdgcn_mfma_f32_16x16x32_bf16(af, bw, an, 0, 0, 0);
    }
    // gate -> gL
    #pragma unroll
    for (int r = 0; r < 4; r++) {
      int crow = mi * 16 + (lane >> 4) * 4 + r;
      int s = s0 + crow;
      float den = denom[(size_t)bh_loc * S_ + s];
      int d = ni * 16 + (lane & 15);
      float vv = b2f(Vb[(vbase + s) * DH + d]);
      float bg = b2f(Bgb[(vbase + s) * DH + d]);
      gL[crow][d] = f2b((vv - an[r] / den) * bg);
    }
    __syncthreads();
    // assoc: this wave owns DK rows [w*48, w*48+48)
    bf16x8 bfr[4];
    #pragma unroll
    for (int n2 = 0; n2 < 4; n2++) {
      bf16x8 bb;
      #pragma unroll
      for (int j = 0; j < 8; j++) bb[j] = (short)gL[kf + j][n2 * 16 + (lane & 15)];
      bfr[n2] = bb;
    }
    #pragma unroll
    for (int m2 = 0; m2 < 3; m2++) {
      int m = w * 48 + m2 * 16 + (lane & 15);
      bf16x8 aa;
      #pragma unroll
      for (int j = 0; j < 8; j++) aa[j] = (short)mkL[kf + j][m];
      #pragma unroll
      for (int n2 = 0; n2 < 4; n2++)
        acc[m2][n2] = __builtin_amdgcn_mfma_f32_16x16x32_bf16(aa, bfr[n2], acc[m2][n2], 0, 0, 0);
    }
    __syncthreads();
  }
  float* pb = part + ((size_t)bh_loc * sk + seg) * (DK * DH);
  #pragma unroll
  for (int m2 = 0; m2 < 3; m2++)
    #pragma unroll
    for (int n2 = 0; n2 < 4; n2++)
      #pragma unroll
      for (int r = 0; r < 4; r++) {
        int m = w * 48 + m2 * 16 + (lane >> 4) * 4 + r;
        int d = n2 * 16 + (lane & 15);
        pb[(size_t)m * DH + d] = acc[m2][n2][r];
      }
}

// ---------------- K5: out = Wmem + sum(parts) ----------------------------------
__global__ __launch_bounds__(256) void k_reduce(
    const float* __restrict__ Wmem, const float* __restrict__ part,
    float* __restrict__ out, int p, int hpd, int sk) {
  size_t idx = (size_t)blockIdx.x * 256 + threadIdx.x;  // over bhl*DK*DH
  int bh_loc = (int)(idx / (DK * DH));
  size_t r = idx - (size_t)bh_loc * (DK * DH);
  int bh_g = (bh_loc / hpd) * H_ + p * hpd + (bh_loc % hpd);
  float acc = Wmem[(size_t)bh_g * (DK * DH) + r];
  for (int k = 0; k < sk; k++)
    acc += part[((size_t)bh_loc * sk + k) * (DK * DH) + r];
  out[(size_t)bh_g * (DK * DH) + r] = acc;
}

extern "C" void kernel_launch(void* const* d_in, const int* in_sizes, int n_in,
                              void* d_out, int out_size, void* d_ws, size_t ws_size,
                              hipStream_t stream) {
  const float* X  = (const float*)d_in[0];
  const float* Wk = (const float*)d_in[1];
  const float* Wv = (const float*)d_in[2];
  const float* Wb = (const float*)d_in[3];
  const float* Wm = (const float*)d_in[4];
  const float* z  = (const float*)d_in[5];
  float* out = (float*)d_out;
  char* ws = (char*)d_ws;

  ushort* Xb    = (ushort*)(ws);
  ushort* Wball = (ushort*)(ws + 33554432ull);
  char*   dyn   = ws + 33554432ull + 6291456ull;

  if (ws_size >= 170000000ull) {
    // -------- Mode A: single-pass projection (needs ~166 MB) --------
    // dyn: kvb 3x33.55MB | mk 25.2MB | denom 0.13MB ; part aliases dead Xb.
    ushort* kvb   = (ushort*)(dyn);
    ushort* mk    = (ushort*)(dyn + 100663296ull);
    float*  denom = (float*) (dyn + 100663296ull + 25165824ull);
    float*  part  = (float*) (ws);                 // alias Xb (dead after proj)
    ushort* Kb  = kvb;
    ushort* Vb  = kvb + (size_t)B_ * H_ * S_ * DH;
    ushort* Bgb = kvb + 2ull * B_ * H_ * S_ * DH;
    const int hpd = 2, bhl = B_ * hpd, sk = 16, s_len = S_ / sk;

    k_cvt <<<dim3(2048), 256, 0, stream>>>(X, Wk, Wv, Wb, Xb, Wball);
    k_proj<<<dim3(128, 8, 3), 256, 0, stream>>>(Xb, Wball, kvb, 0, 0, H_);
    for (int p = 0; p < H_ / hpd; p++) {
      k_dpfp  <<<dim3(bhl * S_ / 4), 256, 0, stream>>>(Kb, z, mk, denom, p, hpd, H_, 1);
      k_fused <<<dim3(sk, bhl), 512, 0, stream>>>(mk, Wm, denom, Vb, Bgb, part,
                                                  p, hpd, H_, 1, sk, s_len);
      k_reduce<<<dim3(bhl * DK * DH / 256), 256, 0, stream>>>(Wm, part, out, p, hpd, sk);
    }
  } else {
    // -------- Mode B: phased projection (round-6 layout, <=141 MB) --------
    int hp = (ws_size >= 145000000ull) ? 4 : 2;
    const int bhl = B_ * hp, nph = H_ / hp, sk = 256 / bhl, s_len = S_ / sk;
    const size_t sect = (size_t)bhl * S_ * DH;       // ushorts per kvb section
    ushort* kvb   = (ushort*)(dyn);
    ushort* mk    = (ushort*)(dyn + 3ull * sect * 2);
    float*  denom = (float*) (dyn + 3ull * sect * 2 + (size_t)bhl * S_ * DK * 2);
    float*  part  = (float*) ((char*)denom + (size_t)bhl * S_ * 4);
    ushort* Kb  = kvb;
    ushort* Vb  = kvb + sect;
    ushort* Bgb = kvb + 2 * sect;

    k_cvt<<<dim3(2048), 256, 0, stream>>>(X, Wk, Wv, Wb, Xb, Wball);
    for (int p = 0; p < nph; p++) {
      k_proj  <<<dim3(128, hp / 2, 3), 256, 0, stream>>>(Xb, Wball, kvb,
                                                         p * hp * DH, p * hp, hp);
      k_dpfp  <<<dim3(bhl * S_ / 4), 256, 0, stream>>>(Kb, z, mk, denom, p, hp, hp, 0);
      k_fused <<<dim3(sk, bhl), 512, 0, stream>>>(mk, Wm, denom, Vb, Bgb, part,
                                                  p, hp, hp, 0, sk, s_len);
      k_reduce<<<dim3(bhl * DK * DH / 256), 256, 0, stream>>>(Wm, part, out, p, hp, sk);
    }
  }
}

// Round 8
// 312.672 us; speedup vs baseline: 1.7271x; 1.4115x over previous
//
#include <hip/hip_runtime.h>
#include <hip/hip_bf16.h>

#define B_ 8
#define S_ 2048
#define DM 1024
#define H_ 16
#define DH 64
#define DK 384

#define AS3 __attribute__((address_space(3)))
#define AS1 __attribute__((address_space(1)))
typedef unsigned int u32;

typedef __attribute__((ext_vector_type(8))) short bf16x8;
typedef __attribute__((ext_vector_type(4))) float f32x4;

static __device__ __forceinline__ ushort f2b(float f) {
  __hip_bfloat16 h = __float2bfloat16(f);
  return *reinterpret_cast<ushort*>(&h);
}
static __device__ __forceinline__ float b2f(ushort u) {
  __hip_bfloat16 h;
  *reinterpret_cast<ushort*>(&h) = u;
  return __bfloat162float(h);
}

// ---------------- K0: convert X and Wk/Wv/Wb to bf16 (once) --------------------
__global__ __launch_bounds__(256) void k_cvt(
    const float* __restrict__ X, const float* __restrict__ Wk,
    const float* __restrict__ Wv, const float* __restrict__ Wb,
    ushort* __restrict__ Xb, ushort* __restrict__ Wball) {
  const int total = 2097152 + 3 * 131072;
  int c = blockIdx.x * 256 + threadIdx.x;
  const int stride = gridDim.x * 256;
  for (; c < total; c += stride) {
    const float* s;
    ushort* d;
    size_t off;
    if (c < 2097152) { s = X; d = Xb; off = (size_t)c; }
    else {
      int cc = c - 2097152;
      int wsel = cc >> 17;
      off = (size_t)(cc & 131071);
      s = wsel == 0 ? Wk : (wsel == 1 ? Wv : Wb);
      d = Wball + (size_t)wsel * (DM * DM);
    }
    float4 a = *(const float4*)(s + off * 8);
    float4 b = *(const float4*)(s + off * 8 + 4);
    ushort u[8] = { f2b(a.x), f2b(a.y), f2b(a.z), f2b(a.w),
                    f2b(b.x), f2b(b.y), f2b(b.z), f2b(b.w) };
    *(uint4*)(d + off * 8) = *(uint4*)u;
  }
}

// ---------------- K1: projection GEMM  Y = Xb @ Wb^T, dbuf + XCD swizzle -------
// Single pass, all 16 heads. Out bf16 [b][h][s][64], kvb sections K|V|sig(B).
__global__ __launch_bounds__(256) void k_proj(
    const ushort* __restrict__ Xb, const ushort* __restrict__ Wball,
    ushort* __restrict__ kvb) {
  __shared__ ushort SH[4 * 8192];              // As[2] | Bs[2]  (64 KB)
  ushort* As = SH;
  ushort* Bs = SH + 2 * 8192;
  const int t = threadIdx.x, lane = t & 63, w = t >> 6;
  const int wm = w >> 1, wn = w & 1;
  // Bijective XCD swizzle: nwg=3072, XCD c gets m-slab [c*16,(c+1)*16) x all n,z
  const int bid = blockIdx.x + (blockIdx.y << 7) + (blockIdx.z << 10);
  const int c = bid & 7, r = bid >> 3;         // r in 0..383
  const int xb = c * 16 + (r & 15);            // m-block 0..127
  const int rest = r >> 4;                     // 0..23
  const int yb = rest & 7, zb = rest >> 3;     // n-block 0..7, wsel 0..2
  const int m0 = xb * 128;
  const int n0 = yb * 128;
  const int wsel = zb;
  const ushort* Wmat = Wball + (size_t)wsel * (DM * DM);
  ushort* out = kvb + (size_t)wsel * ((size_t)B_ * H_ * S_ * DH);

  const int rowst = (lane >> 3);
  const int colsw = ((lane & 7) ^ rowst) << 3;       // pre-swizzled global col

  auto STAGE = [&](int buf, int k0) {
    #pragma unroll
    for (int j = 0; j < 4; j++) {
      int row = (w * 4 + j) * 8 + rowst;
      __builtin_amdgcn_global_load_lds(
          (const AS1 u32*)(Xb + (size_t)(m0 + row) * DM + k0 + colsw),
          (AS3 u32*)(As + buf * 8192 + (w * 4 + j) * 512), 16, 0, 0);
      __builtin_amdgcn_global_load_lds(
          (const AS1 u32*)(Wmat + (size_t)(n0 + row) * DM + k0 + colsw),
          (AS3 u32*)(Bs + buf * 8192 + (w * 4 + j) * 512), 16, 0, 0);
    }
  };

  f32x4 acc[4][4] = {};
  STAGE(0, 0);
  __syncthreads();
  int cur = 0;
  for (int kt = 0; kt < 16; kt++) {
    if (kt < 15) STAGE(cur ^ 1, (kt + 1) * 64);
    const ushort* Ab = As + cur * 8192;
    const ushort* Bb = Bs + cur * 8192;
    #pragma unroll
    for (int kk2 = 0; kk2 < 2; kk2++) {
      const int csw = (((lane >> 4) + 4 * kk2) ^ (lane & 7)) << 3;
      bf16x8 af[4], bfr[4];
      #pragma unroll
      for (int mi = 0; mi < 4; mi++)
        af[mi] = *(const bf16x8*)&Ab[(wm * 64 + mi * 16 + (lane & 15)) * 64 + csw];
      #pragma unroll
      for (int ni = 0; ni < 4; ni++)
        bfr[ni] = *(const bf16x8*)&Bb[(wn * 64 + ni * 16 + (lane & 15)) * 64 + csw];
      #pragma unroll
      for (int mi = 0; mi < 4; mi++)
        #pragma unroll
        for (int ni = 0; ni < 4; ni++)
          acc[mi][ni] = __builtin_amdgcn_mfma_f32_16x16x32_bf16(af[mi], bfr[ni], acc[mi][ni], 0, 0, 0);
    }
    __syncthreads();
    cur ^= 1;
  }

  // Epilogue: LDS bounce, coalesced 2x dwordx4 stores. Cb aliases SH.
  ushort (*Cb)[136] = (ushort (*)[136])SH;
  #pragma unroll
  for (int mi = 0; mi < 4; mi++) {
    __syncthreads();
    #pragma unroll
    for (int ni = 0; ni < 4; ni++)
      #pragma unroll
      for (int rr = 0; rr < 4; rr++) {
        float val = acc[mi][ni][rr];
        if (wsel == 2) val = 1.0f / (1.0f + __expf(-val));
        Cb[wm * 16 + (lane >> 4) * 4 + rr][wn * 64 + ni * 16 + (lane & 15)] = f2b(val);
      }
    __syncthreads();
    int rowL = t >> 3;
    int m = m0 + (rowL >> 4) * 64 + mi * 16 + (rowL & 15);
    int o0 = n0 + (t & 7) * 16;
    int b = m >> 11, s = m & 2047;
    int h = o0 >> 6, d = o0 & 63;
    ushort* dst = out + (((size_t)(b * H_ + h)) * S_ + s) * DH + d;
    uint4 v0 = *(uint4*)&Cb[rowL][(t & 7) * 16];
    uint4 v1 = *(uint4*)&Cb[rowL][(t & 7) * 16 + 8];
    *(uint4*)dst = v0;
    *(uint4*)(dst + 8) = v1;
  }
}

// ---------------- K2: fused DPFP + normalize + num + gate + assoc --------------
// One launch, grid (sk=2, 128 bh), 512 threads. mk never touches HBM.
// All MFMA operands are vector 16B LDS reads (mkL for num-A, WmT for num-B,
// mkT for assoc-A, gLT for assoc-B).
__global__ __launch_bounds__(512) void k_fused2(
    const ushort* __restrict__ Kb, const ushort* __restrict__ Vb,
    const ushort* __restrict__ Bgb, const float* __restrict__ Wmem,
    const float* __restrict__ z, float* __restrict__ part,
    int sk, int s_len) {
  __shared__ ushort WmT[64][392];   // [d][k]
  __shared__ ushort mkL[32][392];   // [s][k]
  __shared__ ushort mkT[384][40];   // [k][s]
  __shared__ ushort gLT[64][40];    // [d][s]
  __shared__ ushort xsb[32][136];   // [s][128] relu features (bf16)
  __shared__ float  zl[384];
  __shared__ float  denL[32];
  const int t = threadIdx.x, lane = t & 63, w = t >> 6;
  const int l15 = lane & 15, lq = lane >> 4, kf = lq * 8;
  const int bh = blockIdx.y, seg = blockIdx.x;
  const size_t rowbase = (size_t)bh * S_;
  const float* Wm = Wmem + (size_t)bh * (DK * DH);
  for (int q = t; q < DK * DH; q += 512) {
    int kk = q >> 6, d = q & 63;
    WmT[d][kk] = f2b(Wm[q]);
  }
  for (int q = t; q < DK; q += 512) zl[q] = z[(size_t)bh * DK + q];
  f32x4 acc[3][4] = {};
  __syncthreads();

  for (int s0 = seg * s_len; s0 < (seg + 1) * s_len; s0 += 32) {
    // 1) K chunk -> relu features xsb
    {
      int row = t >> 4, d0 = (t & 15) * 4;
      ushort4 kv = *(const ushort4*)(Kb + (rowbase + s0 + row) * DH + d0);
      ushort4 xp, xn;
      #pragma unroll
      for (int j = 0; j < 4; j++) {
        float kk = b2f(((const ushort*)&kv)[j]);
        ((ushort*)&xp)[j] = f2b(fmaxf(kk, 0.0f));
        ((ushort*)&xn)[j] = f2b(fmaxf(-kk, 0.0f));
      }
      *(ushort4*)&xsb[row][d0] = xp;
      *(ushort4*)&xsb[row][64 + d0] = xn;
    }
    __syncthreads();
    // 2) DPFP + L2-normalize + denom; row = w*4+lq, lane l15 does f=l15+16i
    {
      int row = w * 4 + lq;
      float v[24];
      float ssq = 0.0f;
      #pragma unroll
      for (int i = 0; i < 24; i++) {
        int f = l15 + 16 * i;
        int jj = f >> 7, i128 = f & 127;
        float val = b2f(xsb[row][i128]) * b2f(xsb[row][(i128 - jj - 1) & 127]);
        v[i] = val;
        ssq += val * val;
      }
      ssq += __shfl_xor(ssq, 1); ssq += __shfl_xor(ssq, 2);
      ssq += __shfl_xor(ssq, 4); ssq += __shfl_xor(ssq, 8);
      float inv = 1.0f / fmaxf(sqrtf(ssq), 1e-12f);
      float ds = 0.0f;
      #pragma unroll
      for (int i = 0; i < 24; i++) {
        int f = l15 + 16 * i;
        ushort nb = f2b(v[i] * inv);
        mkL[row][f] = nb;
        mkT[f][row] = nb;
        ds += zl[f] * b2f(nb);
      }
      ds += __shfl_xor(ds, 1); ds += __shfl_xor(ds, 2);
      ds += __shfl_xor(ds, 4); ds += __shfl_xor(ds, 8);
      if (l15 == 0) denL[row] = ds + 1e-5f;
    }
    __syncthreads();
    // 3) num GEMM (one 16x16 frag per wave) + 4) gate -> gLT
    {
      int mi = w >> 2, ni = w & 3;
      f32x4 an = {};
      #pragma unroll
      for (int k0 = 0; k0 < DK; k0 += 32) {
        bf16x8 af = *(const bf16x8*)&mkL[mi * 16 + l15][k0 + kf];
        bf16x8 bw = *(const bf16x8*)&WmT[ni * 16 + l15][k0 + kf];
        an = __builtin_amdgcn_mfma_f32_16x16x32_bf16(af, bw, an, 0, 0, 0);
      }
      int d = ni * 16 + l15;
      #pragma unroll
      for (int rr = 0; rr < 4; rr++) {
        int crow = mi * 16 + lq * 4 + rr;
        int s = s0 + crow;
        float den = denL[crow];
        float vv = b2f(Vb[(rowbase + s) * DH + d]);
        float bg = b2f(Bgb[(rowbase + s) * DH + d]);
        gLT[d][crow] = f2b((vv - an[rr] / den) * bg);
      }
    }
    __syncthreads();
    // 5) assoc: wave owns feature rows [w*48, w*48+48)
    {
      bf16x8 bfr[4];
      #pragma unroll
      for (int n2 = 0; n2 < 4; n2++)
        bfr[n2] = *(const bf16x8*)&gLT[n2 * 16 + l15][kf];
      #pragma unroll
      for (int m2 = 0; m2 < 3; m2++) {
        bf16x8 aa = *(const bf16x8*)&mkT[w * 48 + m2 * 16 + l15][kf];
        #pragma unroll
        for (int n2 = 0; n2 < 4; n2++)
          acc[m2][n2] = __builtin_amdgcn_mfma_f32_16x16x32_bf16(aa, bfr[n2], acc[m2][n2], 0, 0, 0);
      }
    }
    __syncthreads();
  }

  float* pb = part + ((size_t)bh * sk + seg) * (DK * DH);
  #pragma unroll
  for (int m2 = 0; m2 < 3; m2++)
    #pragma unroll
    for (int n2 = 0; n2 < 4; n2++)
      #pragma unroll
      for (int rr = 0; rr < 4; rr++) {
        int m = w * 48 + m2 * 16 + lq * 4 + rr;
        int d = n2 * 16 + l15;
        pb[(size_t)m * DH + d] = acc[m2][n2][rr];
      }
}

// ---------------- K3: out = Wmem + part0 + part1 (all heads, one launch) -------
__global__ __launch_bounds__(256) void k_reduce(
    const float* __restrict__ Wmem, const float* __restrict__ part,
    float* __restrict__ out) {
  size_t idx = (size_t)blockIdx.x * 256 + threadIdx.x;   // over 128*24576
  int bh = (int)(idx / (DK * DH));
  size_t r = idx - (size_t)bh * (DK * DH);
  out[idx] = Wmem[idx] + part[((size_t)bh * 2) * (DK * DH) + r] +
             part[((size_t)bh * 2 + 1) * (DK * DH) + r];
}

extern "C" void kernel_launch(void* const* d_in, const int* in_sizes, int n_in,
                              void* d_out, int out_size, void* d_ws, size_t ws_size,
                              hipStream_t stream) {
  const float* X  = (const float*)d_in[0];
  const float* Wk = (const float*)d_in[1];
  const float* Wv = (const float*)d_in[2];
  const float* Wb = (const float*)d_in[3];
  const float* Wm = (const float*)d_in[4];
  const float* z  = (const float*)d_in[5];
  float* out = (float*)d_out;
  char* ws = (char*)d_ws;

  // ws layout (needs ~140.6 MB; ws_size >= 170 MB proven by round 7 Mode A):
  //   Xb    : 0          .. 33,554,432   (16384x1024 bf16; dead after k_proj)
  //   Wball : 33,554,432 .. 39,845,888   (3x 1024^2 bf16)
  //   kvb   : 39,845,888 .. 140,509,184  (3 x [b,h,s,64] bf16: K | V | sig(B))
  //   part  : aliases Xb (25.2 MB < 33.5 MB), written after Xb is dead.
  ushort* Xb    = (ushort*)(ws);
  ushort* Wball = (ushort*)(ws + 33554432ull);
  ushort* kvb   = (ushort*)(ws + 39845888ull);
  float*  part  = (float*)(ws);
  ushort* Kb  = kvb;
  ushort* Vb  = kvb + (size_t)B_ * H_ * S_ * DH;
  ushort* Bgb = kvb + 2ull * (size_t)B_ * H_ * S_ * DH;
  const int sk = 2, s_len = S_ / sk;

  k_cvt   <<<dim3(2048), 256, 0, stream>>>(X, Wk, Wv, Wb, Xb, Wball);
  k_proj  <<<dim3(128, 8, 3), 256, 0, stream>>>(Xb, Wball, kvb);
  k_fused2<<<dim3(sk, B_ * H_), 512, 0, stream>>>(Kb, Vb, Bgb, Wm, z, part, sk, s_len);
  k_reduce<<<dim3(B_ * H_ * DK * DH / 256), 256, 0, stream>>>(Wm, part, out);
}